// Round 11
// baseline (48.454 us; speedup 1.0000x reference)
//
#include <hip/hip_runtime.h>
#include <hip/hip_bf16.h>

// ---- problem constants ----
#define BATCH  65536
#define KREAL  784          // 28*28 = GEMM-K (conv folded into Weff)
#define BK     64
#define NCHUNK 13
#define HID    128
#define NOUT   10
#define BM     64           // rows per block
#define NTHR   512          // 8 waves: 4 row-groups x 2 K-halves

using f32x4  = __attribute__((ext_vector_type(4))) float;
using short8 = __attribute__((ext_vector_type(8))) short;   // 8 bf16
using short4v= __attribute__((ext_vector_type(4))) short;   // 4 bf16 (8 B)
using f4     = __attribute__((ext_vector_type(4))) float;

__device__ inline short f2b(float f) {
    union { __hip_bfloat16 h; short s; } u;
    u.h = __float2bfloat16(f);               // hardware RNE cvt
    return u.s;
}
__device__ inline float b2f(unsigned short s) {
    union { unsigned int u; float f; } c; c.u = ((unsigned int)s) << 16;
    return c.f;
}

// global -> LDS direct copy, 16 B per lane. gp: PER-LANE global addr,
// lp: wave-uniform LDS base (HW writes base + lane*16).
#define GLDS16(gp, lp) \
    __builtin_amdgcn_global_load_lds((const __attribute__((address_space(1))) void*)(gp), \
                                     (__attribute__((address_space(3))) void*)(lp), 16, 0, 0)

// ---------------------------------------------------------------------------
// Prep (unchanged, proven):
//  weff_sw[ic][r][cc] = Weff[r][ic*64 + ((cc>>3)^(r&7))*8 + (cc&7)]  (bf16,
//  zero for k>=784) — a linear copy of chunk ic IS the swizzled LDS B-tile.
//  w2f fragment-ordered: ((kk*4+hi)*16+lo)*8+e <-> w2[lo][kk*32+hi*8+e]
// ---------------------------------------------------------------------------
#define NWB (NCHUNK*HID*BK)   // 106496
#define NW2 (4*4*16*8)        // 2048

__global__ void prep_kernel(const float* __restrict__ conv_w,
                            const float* __restrict__ w1,
                            const float* __restrict__ w2,
                            unsigned short* __restrict__ weff_sw,
                            unsigned short* __restrict__ w2f)
{
    int idx = blockIdx.x * 256 + threadIdx.x;
    if (idx < NWB) {
        int ic  = idx >> 13;
        int rem = idx & 8191;
        int r   = rem >> 6;
        int cc  = rem & 63;
        int g   = (cc >> 3) ^ (r & 7);
        int k   = ic * BK + g * 8 + (cc & 7);
        float acc = 0.f;
        if (k < KREAL) {
            int rr = k / 28, c = k - rr * 28;
            #pragma unroll
            for (int di = 0; di < 3; ++di) {
                int i = rr - di;
                if (i >= 0 && i < 26) {
                    #pragma unroll
                    for (int dj = 0; dj < 3; ++dj) {
                        int j = c - dj;
                        if (j >= 0 && j < 26)
                            acc = fmaf(w1[r * 676 + i * 26 + j], conv_w[di * 3 + dj], acc);
                    }
                }
            }
        }
        weff_sw[idx] = (unsigned short)f2b(acc);
    } else {
        int k2 = idx - NWB;
        if (k2 < NW2) {
            int e  = k2 & 7;
            int lo = (k2 >> 3) & 15;
            int hi = (k2 >> 7) & 3;
            int kk = k2 >> 9;
            float v = (lo < NOUT) ? w2[lo * HID + kk * 32 + hi * 8 + e] : 0.f;
            w2f[k2] = (unsigned short)f2b(v);
        }
    }
}

// ---------------------------------------------------------------------------
// Fused: relu(x @ Weff^T + b1) @ w2^T + b2
// K-SPLIT for occupancy: 8 waves/block = 4 row-groups (16 rows) x 2 K-halves.
// Wave (g,kh) computes partial C over k-substep kh of every chunk (8 MFMAs).
// A-tile granules are (g,kh)-private under the XOR swizzle (complementary
// physical sets) -> A needs no barrier ever. B identical to r10. Partial
// accs reduced once at the end via bf16 LDS scratch. launch_bounds(512,7)
// caps VGPR at 73 -> 24 waves/CU (1.5x r10's TLP). Stagger kept.
// ---------------------------------------------------------------------------
__global__ __launch_bounds__(NTHR, 7)
void fused_mlp_kernel(const float* __restrict__ x,
                      const float* __restrict__ b1,
                      const float* __restrict__ b2,
                      const unsigned short* __restrict__ weff_sw,
                      const unsigned short* __restrict__ w2f,
                      float* __restrict__ out)
{
    __shared__ __align__(16) unsigned char smem[40960];      // 40 KB
    unsigned short* ldsA  = (unsigned short*)smem;           // [64][64] bf16 swz, 8 KB
    unsigned short* ldsB0 = (unsigned short*)(smem + 8192);  // [128][64] bf16 swz, 16 KB
    unsigned short* ldsB1 = (unsigned short*)(smem + 24576);
    unsigned short* ldsH  = (unsigned short*)smem;           // [64][128] alias (post-loop)
    unsigned short* scrP  = (unsigned short*)(smem + 16384); // 4x[16][128] bf16 (post-loop)
    float*          outS  = (float*)(smem + 32768);          // [64][10] f32 (post-loop)

    const int tid  = threadIdx.x;
    const int wv   = tid >> 6;
    const int lane = tid & 63;
    const int lo   = lane & 15;
    const int hi   = lane >> 4;
    const int g    = wv >> 1;                // row-group 0..3
    const int kh   = wv & 1;                 // K-half 0..1
    const int row0 = blockIdx.x * BM;
    const int wr0  = g * 16;
    const int c0   = blockIdx.x % NCHUNK;    // stagger start chunk

    f32x4 acc[8];
    #pragma unroll
    for (int t = 0; t < 8; ++t) acc[t] = (f32x4){0.f, 0.f, 0.f, 0.f};

    // A staging: wave loads its 16 rows x its 32-col half. Instr j covers
    // rows wr0+j*8+(lane>>3), 8 lanes x 16 B = 128-B run per row.
    const char* abase = (const char*)(x + (long)(row0 + wr0 + (lane >> 3)) * KREAL);
    f4 av[2];
    auto issueA = [&](int ic) {
        #pragma unroll
        for (int j = 0; j < 2; ++j) {
            int ce = ic * BK + kh * 32 + (lane & 7) * 4;
            int cb = (ce + 4 <= KREAL) ? ce : 0;   // clamp; weff zero for k>=784
            av[j] = *(const f4*)(abase + (long)j * 8 * KREAL * 4 + (long)cb * 4);
        }
    };
    // cvt + swizzled b64 writes: logical granule cg at phys cg^(r&7).
    // kh=0 writes cg 0..3, kh=1 writes 4..7 -> physical sets complementary.
    auto writeA = [&]() {
        #pragma unroll
        for (int j = 0; j < 2; ++j) {
            int r  = wr0 + j * 8 + (lane >> 3);
            int cg = kh * 4 + ((lane & 7) >> 1);
            short4v c;
            c[0] = f2b(av[j][0]); c[1] = f2b(av[j][1]);
            c[2] = f2b(av[j][2]); c[3] = f2b(av[j][3]);
            int off = r * 128 + ((cg ^ (r & 7)) << 4) + ((lane & 1) << 3);
            *(short4v*)((char*)ldsA + off) = c;
        }
    };
    auto stageB = [&](int ic, unsigned short* dst) {
        const char* src = (const char*)(weff_sw + (long)ic * (HID * BK));
        #pragma unroll
        for (int j = 0; j < 2; ++j)
            GLDS16(src + wv * 2048 + j * 1024 + lane * 16,
                   (char*)dst + wv * 2048 + j * 1024);
    };

    // ---- prologue: chunk c0 ----
    issueA(c0);                              // 2 reg loads (oldest)
    stageB(c0, ldsB0);                       // 2 glds
    writeA();                                // compiler waits only av (vmcnt(2))
    asm volatile("s_waitcnt vmcnt(0)" ::: "memory");
    __builtin_amdgcn_sched_barrier(0);
    __builtin_amdgcn_s_barrier();            // first chunk visible
    __builtin_amdgcn_sched_barrier(0);

    #pragma unroll
    for (int s = 0; s < NCHUNK; ++s) {
        int ic  = c0 + s;     if (ic >= NCHUNK)  ic -= NCHUNK;
        int icn = ic + 1;     if (icn >= NCHUNK) icn -= NCHUNK;
        const unsigned short* Bc = (s & 1) ? ldsB1 : ldsB0;
        if (s + 1 < NCHUNK) {
            issueA(icn);                     // av loads first (oldest)
            stageB(icn, (s & 1) ? ldsB0 : ldsB1);   // WAR-safe: entry barrier
        }
        // ---- compute: this wave's K-half of chunk ic (8 MFMAs) ----
        {
            const int r = wr0 + lo;
            const int G = kh * 4 + hi;       // granule16 within the 64-col chunk
            short8 af = *(const short8*)((const char*)ldsA + r * 128 + ((G ^ (r & 7)) << 4));
            #pragma unroll
            for (int t = 0; t < 8; ++t) {
                const int ob = t * 16 + lo;
                short8 bfrag = *(const short8*)&Bc[ob * BK + ((G ^ (ob & 7)) << 3)];
                acc[t] = __builtin_amdgcn_mfma_f32_16x16x32_bf16(af, bfrag, acc[t], 0, 0, 0);
            }
        }
        if (s + 1 < NCHUNK) {
            __builtin_amdgcn_sched_barrier(0);
            writeA();                        // own rows+granules, after own reads
            __builtin_amdgcn_sched_barrier(0);
            asm volatile("s_waitcnt vmcnt(0)" ::: "memory");   // B(icn) landed
            __builtin_amdgcn_sched_barrier(0);
            __builtin_amdgcn_s_barrier();    // next chunk visible block-wide
            __builtin_amdgcn_sched_barrier(0);
        }
    }

    __builtin_amdgcn_sched_barrier(0);
    __builtin_amdgcn_s_barrier();            // all compute done; B buffers dead
    __builtin_amdgcn_sched_barrier(0);

    // ---- K-half reduction: kh=1 waves publish partial C (bf16) ----
    unsigned short* scr = scrP + g * 2048;   // [16][128] bf16 per group
    if (kh == 1) {
        #pragma unroll
        for (int t = 0; t < 8; ++t)
            #pragma unroll
            for (int j = 0; j < 4; ++j)
                scr[(hi * 4 + j) * 128 + t * 16 + lo] = (unsigned short)f2b(acc[t][j]);
    }
    __syncthreads();

    if (kh == 0) {
        // ---- merge halves + FC1 epilogue: +b1, ReLU, h -> swizzled ldsH ----
        #pragma unroll
        for (int t = 0; t < 8; ++t) {
            float bias = b1[t * 16 + lo];
            #pragma unroll
            for (int j = 0; j < 4; ++j) {
                float hv = acc[t][j] + b2f(scr[(hi * 4 + j) * 128 + t * 16 + lo]) + bias;
                hv = hv > 0.f ? hv : 0.f;
                int rloc = wr0 + hi * 4 + j;
                int col  = t * 16 + lo;
                int gg   = col >> 3, e = col & 7;
                ldsH[rloc * HID + ((gg ^ (rloc & 7)) << 3) + e] = (unsigned short)f2b(hv);
            }
        }
        // wave reads only its own writes below -> no barrier

        // ---- FC2: h[16x128] @ w2^T[128x16], 4 MFMAs ----
        f32x4 acc2 = (f32x4){0.f, 0.f, 0.f, 0.f};
        #pragma unroll
        for (int kk = 0; kk < 4; ++kk) {
            int r  = wr0 + lo;
            int gg = kk * 4 + hi;
            short8 ha = *(const short8*)&ldsH[r * HID + ((gg ^ (r & 7)) << 3)];
            short8 wb = *(const short8*)(w2f + (((kk * 4 + hi) * 16 + lo) << 3));
            acc2 = __builtin_amdgcn_mfma_f32_16x16x32_bf16(ha, wb, acc2, 0, 0, 0);
        }
        // stage [16][10] f32, then one contiguous 640-B store
        float* os = outS + g * 160;
        if (lo < NOUT) {
            float bb = b2[lo];
            #pragma unroll
            for (int j = 0; j < 4; ++j)
                os[(hi * 4 + j) * NOUT + lo] = acc2[j] + bb;
        }
        if (lane < 40) {
            f4 v = *(const f4*)&os[lane * 4];
            *(f4*)(out + (long)(row0 + wr0) * NOUT + lane * 4) = v;
        }
    }
}

// ---------------------------------------------------------------------------
extern "C" void kernel_launch(void* const* d_in, const int* in_sizes, int n_in,
                              void* d_out, int out_size, void* d_ws, size_t ws_size,
                              hipStream_t stream)
{
    const float* x      = (const float*)d_in[0];
    const float* conv_w = (const float*)d_in[1];
    const float* w1     = (const float*)d_in[2];
    const float* b1     = (const float*)d_in[3];
    const float* w2     = (const float*)d_in[4];
    const float* b2     = (const float*)d_in[5];
    float* out = (float*)d_out;

    unsigned short* weff_sw = (unsigned short*)d_ws;    // 106496 bf16
    unsigned short* w2f     = weff_sw + NWB;            // 2048 bf16

    const int prep_total = NWB + NW2;                   // 108544
    prep_kernel<<<(prep_total + 255) / 256, 256, 0, stream>>>(conv_w, w1, w2, weff_sw, w2f);
    fused_mlp_kernel<<<BATCH / BM, NTHR, 0, stream>>>(x, b1, b2, weff_sw, w2f, out);
}

// Round 12
// 43.941 us; speedup vs baseline: 1.1027x; 1.1027x over previous
//
#include <hip/hip_runtime.h>
#include <hip/hip_bf16.h>

// ---- problem constants ----
#define BATCH  65536
#define KREAL  784          // 28*28 = GEMM-K (conv folded into Weff)
#define BK     64
#define NCHUNK 13
#define HID    128
#define NOUT   10
#define BM     64           // rows per block
#define NTHR   256          // 4 waves; grid = 1024 = exactly 4 blocks/CU

using f32x4  = __attribute__((ext_vector_type(4))) float;
using short8 = __attribute__((ext_vector_type(8))) short;   // 8 bf16
using short4v= __attribute__((ext_vector_type(4))) short;   // 4 bf16 (8 B)
using f4     = __attribute__((ext_vector_type(4))) float;

__device__ inline short f2b(float f) {
    union { __hip_bfloat16 h; short s; } u;
    u.h = __float2bfloat16(f);               // hardware RNE cvt
    return u.s;
}

// global -> LDS direct copy, 16 B per lane. gp: PER-LANE global addr,
// lp: wave-uniform LDS base (HW writes base + lane*16).
#define GLDS16(gp, lp) \
    __builtin_amdgcn_global_load_lds((const __attribute__((address_space(1))) void*)(gp), \
                                     (__attribute__((address_space(3))) void*)(lp), 16, 0, 0)

// ---------------------------------------------------------------------------
// Prep (unchanged, proven):
//  weff_sw[ic][r][cc] = Weff[r][ic*64 + ((cc>>3)^(r&7))*8 + (cc&7)]  (bf16,
//  zero for k>=784) — a linear copy of chunk ic IS the swizzled LDS B-tile.
//  w2f fragment-ordered: ((kk*4+hi)*16+lo)*8+e <-> w2[lo][kk*32+hi*8+e]
// ---------------------------------------------------------------------------
#define NWB (NCHUNK*HID*BK)   // 106496
#define NW2 (4*4*16*8)        // 2048

__global__ void prep_kernel(const float* __restrict__ conv_w,
                            const float* __restrict__ w1,
                            const float* __restrict__ w2,
                            unsigned short* __restrict__ weff_sw,
                            unsigned short* __restrict__ w2f)
{
    int idx = blockIdx.x * 256 + threadIdx.x;
    if (idx < NWB) {
        int ic  = idx >> 13;
        int rem = idx & 8191;
        int r   = rem >> 6;
        int cc  = rem & 63;
        int g   = (cc >> 3) ^ (r & 7);
        int k   = ic * BK + g * 8 + (cc & 7);
        float acc = 0.f;
        if (k < KREAL) {
            int rr = k / 28, c = k - rr * 28;
            #pragma unroll
            for (int di = 0; di < 3; ++di) {
                int i = rr - di;
                if (i >= 0 && i < 26) {
                    #pragma unroll
                    for (int dj = 0; dj < 3; ++dj) {
                        int j = c - dj;
                        if (j >= 0 && j < 26)
                            acc = fmaf(w1[r * 676 + i * 26 + j], conv_w[di * 3 + dj], acc);
                    }
                }
            }
        }
        weff_sw[idx] = (unsigned short)f2b(acc);
    } else {
        int k2 = idx - NWB;
        if (k2 < NW2) {
            int e  = k2 & 7;
            int lo = (k2 >> 3) & 15;
            int hi = (k2 >> 7) & 3;
            int kk = k2 >> 9;
            float v = (lo < NOUT) ? w2[lo * HID + kk * 32 + hi * 8 + e] : 0.f;
            w2f[k2] = (unsigned short)f2b(v);
        }
    }
}

// ---------------------------------------------------------------------------
// Fused: relu(x @ Weff^T + b1) @ w2^T + b2
// r10 skeleton + DEPTH-2 A prefetch, SINGLE-buffer B:
//  per chunk: stageB(ic) [L2-hot glds] -> issueA(ic+2) [2 chunks to land]
//  -> vmcnt(4) [waits B(ic) AND A(ic+1); only A(ic+2) stays in flight]
//  -> bare barrier -> 16 MFMAs -> writeA(A(ic+1), zero-stall, wave-private)
//  -> bare barrier [B WAR]. LDS 32 KB -> 4 blocks/CU, 16 waves/CU. Stagger.
// ---------------------------------------------------------------------------
__global__ __launch_bounds__(NTHR, 4)
void fused_mlp_kernel(const float* __restrict__ x,
                      const float* __restrict__ b1,
                      const float* __restrict__ b2,
                      const unsigned short* __restrict__ weff_sw,
                      const unsigned short* __restrict__ w2f,
                      float* __restrict__ out)
{
    __shared__ __align__(16) unsigned char smem[32768];      // 32 KB
    unsigned short* ldsA0 = (unsigned short*)smem;           // [64][64] bf16 swz, 8 KB
    unsigned short* ldsA1 = (unsigned short*)(smem + 8192);
    unsigned short* ldsB  = (unsigned short*)(smem + 16384); // [128][64] bf16 swz, 16 KB
    unsigned short* ldsH  = (unsigned short*)smem;           // [64][128] alias (post-loop)
    float*          outS  = (float*)(smem + 16384);          // [64][10] f32 alias (post-loop)

    const int tid  = threadIdx.x;
    const int wv   = tid >> 6;
    const int lane = tid & 63;
    const int lo   = lane & 15;
    const int hi   = lane >> 4;
    const int row0 = blockIdx.x * BM;
    const int wr0  = wv * 16;
    const int c0   = blockIdx.x % NCHUNK;    // stagger start chunk

    f32x4 acc[8];
    #pragma unroll
    for (int t = 0; t < 8; ++t) acc[t] = (f32x4){0.f, 0.f, 0.f, 0.f};

    // A staging: instr j covers rows wr0+j*4+hi, 16 lanes x 16 B = 256 B/row run.
    const char* abase = (const char*)(x + (long)(row0 + wr0 + hi) * KREAL);
    f4 av0[4], av1[4];
    auto issueA = [&](int ic, f4 (&v)[4]) {
        #pragma unroll
        for (int j = 0; j < 4; ++j) {
            int ce = ic * BK + lo * 4;
            int cb = (ce + 4 <= KREAL) ? ce : 0;   // clamp; weff zero for k>=784
            v[j] = *(const f4*)(abase + (long)j * 4 * KREAL * 4 + (long)cb * 4);
        }
    };
    // cvt + swizzled b64 writes into the wave's OWN rows (wave-private).
    auto writeA = [&](f4 (&v)[4], unsigned short* dstA) {
        #pragma unroll
        for (int j = 0; j < 4; ++j) {
            int r = wr0 + j * 4 + hi;
            short4v c;
            c[0] = f2b(v[j][0]); c[1] = f2b(v[j][1]);
            c[2] = f2b(v[j][2]); c[3] = f2b(v[j][3]);
            int byteoff = r * 128 + ((((lo >> 1) ^ (r & 7)) << 4)) + ((lo & 1) << 3);
            *(short4v*)((char*)dstA + byteoff) = c;
        }
    };
    auto stageB = [&](int ic) {
        const char* src = (const char*)(weff_sw + (long)ic * (HID * BK));
        #pragma unroll
        for (int j = 0; j < 4; ++j)
            GLDS16(src + wv * 4096 + j * 1024 + lane * 16,
                   (char*)ldsB + wv * 4096 + j * 1024);
    };

    // ---- prologue: A(c0) -> ldsA0, A(c0+1) in flight ----
    {
        int c1 = (c0 + 1 < NCHUNK) ? c0 + 1 : c0 + 1 - NCHUNK;
        issueA(c0, av0);                     // 4 loads (oldest)
        issueA(c1, av1);                     // 4 loads
        asm volatile("s_waitcnt vmcnt(4)" ::: "memory");   // av0 landed
        __builtin_amdgcn_sched_barrier(0);
        writeA(av0, ldsA0);                  // wave-private; no barrier
        __builtin_amdgcn_sched_barrier(0);
    }

    #pragma unroll
    for (int s = 0; s < NCHUNK; ++s) {
        int ic  = c0 + s;      if (ic  >= NCHUNK) ic  -= NCHUNK;
        int ic2 = ic + 2;      if (ic2 >= NCHUNK) ic2 -= NCHUNK;
        const unsigned short* Acur = (s & 1) ? ldsA1 : ldsA0;
        unsigned short*       Anxt = (s & 1) ? ldsA0 : ldsA1;

        stageB(ic);                          // 4 glds (WAR-safe: tail barrier of s-1)
        if (s + 2 < NCHUNK) {
            if (s & 1) issueA(ic2, av1); else issueA(ic2, av0);  // 4 loads, 2 chunks to land
            asm volatile("s_waitcnt vmcnt(4)" ::: "memory");     // B(ic)+A(ic+1) done
        } else {
            asm volatile("s_waitcnt vmcnt(0)" ::: "memory");
        }
        __builtin_amdgcn_sched_barrier(0);
        __builtin_amdgcn_s_barrier();        // Blds visible block-wide (bare, no drain)
        __builtin_amdgcn_sched_barrier(0);

        // ---- compute chunk ic: 2 k-substeps x 8 n-tiles ----
        const int r = wr0 + lo;
        #pragma unroll
        for (int kk = 0; kk < 2; ++kk) {
            const int G = kk * 4 + hi;
            short8 af = *(const short8*)((const char*)Acur + r * 128 + ((G ^ (r & 7)) << 4));
            #pragma unroll
            for (int t = 0; t < 8; ++t) {
                const int ob = t * 16 + lo;
                short8 bfrag = *(const short8*)&ldsB[ob * BK + ((G ^ (ob & 7)) << 3)];
                acc[t] = __builtin_amdgcn_mfma_f32_16x16x32_bf16(af, bfrag, acc[t], 0, 0, 0);
            }
        }

        if (s + 1 < NCHUNK) {
            __builtin_amdgcn_sched_barrier(0);
            if (s & 1) writeA(av0, Anxt); else writeA(av1, Anxt);  // A(ic+1), landed
            __builtin_amdgcn_sched_barrier(0);
            __builtin_amdgcn_s_barrier();    // all waves done reading Blds (bare)
            __builtin_amdgcn_sched_barrier(0);
        }
    }

    __builtin_amdgcn_sched_barrier(0);
    __builtin_amdgcn_s_barrier();            // all compute done before alias writes
    __builtin_amdgcn_sched_barrier(0);

    // ---- FC1 epilogue: +b1, ReLU, h -> swizzled per-wave ldsH slice ----
    // C/D layout: col = lane&15, row = (lane>>4)*4 + reg
    #pragma unroll
    for (int t = 0; t < 8; ++t) {
        float bias = b1[t * 16 + lo];
        #pragma unroll
        for (int j = 0; j < 4; ++j) {
            float hv = acc[t][j] + bias;
            hv = hv > 0.f ? hv : 0.f;
            int rloc = wr0 + hi * 4 + j;
            int col  = t * 16 + lo;
            int g    = col >> 3, e = col & 7;
            ldsH[rloc * HID + ((g ^ (rloc & 7)) << 3) + e] = (unsigned short)f2b(hv);
        }
    }
    // wave reads only its own writes below -> no barrier

    // ---- FC2: h[16x128] @ w2^T[128x16] per wave, 4 MFMAs ----
    f32x4 acc2 = (f32x4){0.f, 0.f, 0.f, 0.f};
    #pragma unroll
    for (int kk = 0; kk < 4; ++kk) {
        int r = wr0 + lo;
        int g = kk * 4 + hi;
        short8 ha = *(const short8*)&ldsH[r * HID + ((g ^ (r & 7)) << 3)];
        short8 wb = *(const short8*)(w2f + (((kk * 4 + hi) * 16 + lo) << 3));
        acc2 = __builtin_amdgcn_mfma_f32_16x16x32_bf16(ha, wb, acc2, 0, 0, 0);
    }
    // stage [16][10] f32 in the wave's outS slice, then one contiguous 640-B store
    float* os = outS + wv * 160;
    if (lo < NOUT) {
        float bb = b2[lo];
        #pragma unroll
        for (int j = 0; j < 4; ++j)
            os[(hi * 4 + j) * NOUT + lo] = acc2[j] + bb;
    }
    if (lane < 40) {
        f4 v = *(const f4*)&os[lane * 4];
        *(f4*)(out + (long)(row0 + wr0) * NOUT + lane * 4) = v;
    }
}

// ---------------------------------------------------------------------------
extern "C" void kernel_launch(void* const* d_in, const int* in_sizes, int n_in,
                              void* d_out, int out_size, void* d_ws, size_t ws_size,
                              hipStream_t stream)
{
    const float* x      = (const float*)d_in[0];
    const float* conv_w = (const float*)d_in[1];
    const float* w1     = (const float*)d_in[2];
    const float* b1     = (const float*)d_in[3];
    const float* w2     = (const float*)d_in[4];
    const float* b2     = (const float*)d_in[5];
    float* out = (float*)d_out;

    unsigned short* weff_sw = (unsigned short*)d_ws;    // 106496 bf16
    unsigned short* w2f     = weff_sw + NWB;            // 2048 bf16

    const int prep_total = NWB + NW2;                   // 108544
    prep_kernel<<<(prep_total + 255) / 256, 256, 0, stream>>>(conv_w, w1, w2, weff_sw, w2f);
    fused_mlp_kernel<<<BATCH / BM, NTHR, 0, stream>>>(x, b1, b2, weff_sw, w2f, out);
}

// Round 14
// 43.288 us; speedup vs baseline: 1.1193x; 1.0151x over previous
//
#include <hip/hip_runtime.h>
#include <hip/hip_bf16.h>

// ---- problem constants ----
#define BATCH  65536
#define KREAL  784          // 28*28 = GEMM-K (conv folded into Weff)
#define BK     64
#define NCHUNK 13
#define HID    128
#define NOUT   10
#define BM     64           // rows per block
#define NTHR   256          // 4 waves; grid = 1024 = exactly 4 blocks/CU

using f32x4  = __attribute__((ext_vector_type(4))) float;
using short8 = __attribute__((ext_vector_type(8))) short;   // 8 bf16
using short4v= __attribute__((ext_vector_type(4))) short;   // 4 bf16 (8 B)
using f4     = __attribute__((ext_vector_type(4))) float;

__device__ inline short f2b(float f) {
    union { __hip_bfloat16 h; short s; } u;
    u.h = __float2bfloat16(f);               // hardware RNE cvt
    return u.s;
}

// global -> LDS direct copy, 16 B per lane. gp: PER-LANE global addr,
// lp: wave-uniform LDS base (HW writes base + lane*16).
#define GLDS16(gp, lp) \
    __builtin_amdgcn_global_load_lds((const __attribute__((address_space(1))) void*)(gp), \
                                     (__attribute__((address_space(3))) void*)(lp), 16, 0, 0)

// ---------------------------------------------------------------------------
// Prep (proven):
//  weff_sw[ic][r][cc] = Weff[r][ic*64 + ((cc>>3)^(r&7))*8 + (cc&7)]  (bf16,
//  zero for k>=784) — a linear copy of chunk ic IS the swizzled LDS B-tile.
//  w2f fragment-ordered: ((kk*4+hi)*16+lo)*8+e <-> w2[lo][kk*32+hi*8+e]
// ---------------------------------------------------------------------------
#define NWB (NCHUNK*HID*BK)   // 106496
#define NW2 (4*4*16*8)        // 2048

__global__ void prep_kernel(const float* __restrict__ conv_w,
                            const float* __restrict__ w1,
                            const float* __restrict__ w2,
                            unsigned short* __restrict__ weff_sw,
                            unsigned short* __restrict__ w2f)
{
    int idx = blockIdx.x * 256 + threadIdx.x;
    if (idx < NWB) {
        int ic  = idx >> 13;
        int rem = idx & 8191;
        int r   = rem >> 6;
        int cc  = rem & 63;
        int g   = (cc >> 3) ^ (r & 7);
        int k   = ic * BK + g * 8 + (cc & 7);
        float acc = 0.f;
        if (k < KREAL) {
            int rr = k / 28, c = k - rr * 28;
            #pragma unroll
            for (int di = 0; di < 3; ++di) {
                int i = rr - di;
                if (i >= 0 && i < 26) {
                    #pragma unroll
                    for (int dj = 0; dj < 3; ++dj) {
                        int j = c - dj;
                        if (j >= 0 && j < 26)
                            acc = fmaf(w1[r * 676 + i * 26 + j], conv_w[di * 3 + dj], acc);
                    }
                }
            }
        }
        weff_sw[idx] = (unsigned short)f2b(acc);
    } else {
        int k2 = idx - NWB;
        if (k2 < NW2) {
            int e  = k2 & 7;
            int lo = (k2 >> 3) & 15;
            int hi = (k2 >> 7) & 3;
            int kk = k2 >> 9;
            float v = (lo < NOUT) ? w2[lo * HID + kk * 32 + hi * 8 + e] : 0.f;
            w2f[k2] = (unsigned short)f2b(v);
        }
    }
}

// ---------------------------------------------------------------------------
// Fused: relu(x @ Weff^T + b1) @ w2^T + b2
// BM=64, 256 thr (4 waves), 1024 blocks = 4 blocks/CU (16 waves/CU, LDS
// 40 KB exact fit). Chunk-STAGGERED K-sweep: block b starts at chunk b%13
// (de-phases weff L2 + x column herd). A: reg-staged, single LDS buffer,
// wave-private rows (writeA after own reads; per-wave DS in-order). B:
// pre-swizzled weff via global_load_lds, double-buffered. One bare
// s_barrier + one vmcnt(0) per chunk, after the compute overlap window.
// Best measured: 43.3 us total (r10).
// ---------------------------------------------------------------------------
__global__ __launch_bounds__(NTHR, 4)
void fused_mlp_kernel(const float* __restrict__ x,
                      const float* __restrict__ b1,
                      const float* __restrict__ b2,
                      const unsigned short* __restrict__ weff_sw,
                      const unsigned short* __restrict__ w2f,
                      float* __restrict__ out)
{
    __shared__ __align__(16) unsigned char smem[40960];      // 40 KB
    unsigned short* ldsA  = (unsigned short*)smem;           // [64][64] bf16 swz, 8 KB (single)
    unsigned short* ldsB0 = (unsigned short*)(smem + 8192);  // [128][64] bf16 swz, 16 KB
    unsigned short* ldsB1 = (unsigned short*)(smem + 24576);
    unsigned short* ldsH  = (unsigned short*)smem;           // [64][128] alias (post-loop)
    float*          outS  = (float*)(smem + 16384);          // [64][10] f32 alias (post-loop)

    const int tid  = threadIdx.x;
    const int wv   = tid >> 6;
    const int lane = tid & 63;
    const int lo   = lane & 15;
    const int hi   = lane >> 4;
    const int row0 = blockIdx.x * BM;
    const int wr0  = wv * 16;
    const int c0   = blockIdx.x % NCHUNK;    // stagger start chunk

    f32x4 acc[8];
    #pragma unroll
    for (int t = 0; t < 8; ++t) acc[t] = (f32x4){0.f, 0.f, 0.f, 0.f};

    // A staging: instr j covers rows wr0+j*4+hi, 16 lanes x 16 B = 256 B/row run.
    const char* abase = (const char*)(x + (long)(row0 + wr0 + hi) * KREAL);
    f4 av[4];
    auto issueA = [&](int ic) {
        #pragma unroll
        for (int j = 0; j < 4; ++j) {
            int ce = ic * BK + lo * 4;
            int cb = (ce + 4 <= KREAL) ? ce : 0;   // clamp; weff zero for k>=784
            av[j] = *(const f4*)(abase + (long)j * 4 * KREAL * 4 + (long)cb * 4);
        }
    };
    // cvt + swizzled b64 writes into the wave's OWN rows (wave-private).
    auto writeA = [&]() {
        #pragma unroll
        for (int j = 0; j < 4; ++j) {
            int r = wr0 + j * 4 + hi;
            short4v c;
            c[0] = f2b(av[j][0]); c[1] = f2b(av[j][1]);
            c[2] = f2b(av[j][2]); c[3] = f2b(av[j][3]);
            int byteoff = r * 128 + ((((lo >> 1) ^ (r & 7)) << 4)) + ((lo & 1) << 3);
            *(short4v*)((char*)ldsA + byteoff) = c;
        }
    };
    auto stageB = [&](int ic, unsigned short* dst) {
        const char* src = (const char*)(weff_sw + (long)ic * (HID * BK));
        #pragma unroll
        for (int j = 0; j < 4; ++j)
            GLDS16(src + wv * 4096 + j * 1024 + lane * 16,
                   (char*)dst + wv * 4096 + j * 1024);
    };

    // ---- prologue: chunk c0 ----
    issueA(c0);                              // 4 reg loads (oldest)
    stageB(c0, ldsB0);                       // 4 glds
    writeA();                                // compiler waits only the av loads
    asm volatile("s_waitcnt vmcnt(0)" ::: "memory");
    __builtin_amdgcn_sched_barrier(0);
    __builtin_amdgcn_s_barrier();            // A+B of first chunk visible
    __builtin_amdgcn_sched_barrier(0);

    #pragma unroll
    for (int s = 0; s < NCHUNK; ++s) {
        int ic  = c0 + s;     if (ic >= NCHUNK)  ic -= NCHUNK;
        int icn = ic + 1;     if (icn >= NCHUNK) icn -= NCHUNK;
        const unsigned short* Bc = (s & 1) ? ldsB1 : ldsB0;
        if (s + 1 < NCHUNK) {
            issueA(icn);                     // av loads first (oldest)
            stageB(icn, (s & 1) ? ldsB0 : ldsB1);   // WAR-safe: entry barrier
        }
        // ---- compute chunk ic ----
        const int r = wr0 + lo;
        #pragma unroll
        for (int kk = 0; kk < 2; ++kk) {
            const int G = kk * 4 + hi;
            short8 af = *(const short8*)((const char*)ldsA + r * 128 + ((G ^ (r & 7)) << 4));
            #pragma unroll
            for (int t = 0; t < 8; ++t) {
                const int ob = t * 16 + lo;
                short8 bfrag = *(const short8*)&Bc[ob * BK + ((G ^ (ob & 7)) << 3)];
                acc[t] = __builtin_amdgcn_mfma_f32_16x16x32_bf16(af, bfrag, acc[t], 0, 0, 0);
            }
        }
        if (s + 1 < NCHUNK) {
            __builtin_amdgcn_sched_barrier(0);
            writeA();                        // own rows, after own reads (DS in-order);
                                             // compiler-waits av only, B still in flight
            __builtin_amdgcn_sched_barrier(0);
            asm volatile("s_waitcnt vmcnt(0)" ::: "memory");   // B(icn) landed
            __builtin_amdgcn_sched_barrier(0);
            __builtin_amdgcn_s_barrier();    // next chunk visible block-wide
            __builtin_amdgcn_sched_barrier(0);
        }
    }

    __builtin_amdgcn_sched_barrier(0);
    __builtin_amdgcn_s_barrier();            // all compute done before alias writes
    __builtin_amdgcn_sched_barrier(0);

    // ---- FC1 epilogue: +b1, ReLU, h -> swizzled per-wave ldsH slice ----
    // C/D layout: col = lane&15, row = (lane>>4)*4 + reg
    #pragma unroll
    for (int t = 0; t < 8; ++t) {
        float bias = b1[t * 16 + lo];
        #pragma unroll
        for (int j = 0; j < 4; ++j) {
            float hv = acc[t][j] + bias;
            hv = hv > 0.f ? hv : 0.f;
            int rloc = wr0 + hi * 4 + j;
            int col  = t * 16 + lo;
            int g    = col >> 3, e = col & 7;
            ldsH[rloc * HID + ((g ^ (rloc & 7)) << 3) + e] = (unsigned short)f2b(hv);
        }
    }
    // wave reads only its own writes below -> no barrier

    // ---- FC2: h[16x128] @ w2^T[128x16] per wave, 4 MFMAs ----
    f32x4 acc2 = (f32x4){0.f, 0.f, 0.f, 0.f};
    #pragma unroll
    for (int kk = 0; kk < 4; ++kk) {
        int r = wr0 + lo;
        int g = kk * 4 + hi;
        short8 ha = *(const short8*)&ldsH[r * HID + ((g ^ (r & 7)) << 3)];
        short8 wb = *(const short8*)(w2f + (((kk * 4 + hi) * 16 + lo) << 3));
        acc2 = __builtin_amdgcn_mfma_f32_16x16x32_bf16(ha, wb, acc2, 0, 0, 0);
    }
    // stage [16][10] f32 in the wave's outS slice, then one contiguous 640-B store
    float* os = outS + wv * 160;
    if (lo < NOUT) {
        float bb = b2[lo];
        #pragma unroll
        for (int j = 0; j < 4; ++j)
            os[(hi * 4 + j) * NOUT + lo] = acc2[j] + bb;
    }
    if (lane < 40) {
        f4 v = *(const f4*)&os[lane * 4];
        *(f4*)(out + (long)(row0 + wr0) * NOUT + lane * 4) = v;
    }
}

// ---------------------------------------------------------------------------
extern "C" void kernel_launch(void* const* d_in, const int* in_sizes, int n_in,
                              void* d_out, int out_size, void* d_ws, size_t ws_size,
                              hipStream_t stream)
{
    const float* x      = (const float*)d_in[0];
    const float* conv_w = (const float*)d_in[1];
    const float* w1     = (const float*)d_in[2];
    const float* b1     = (const float*)d_in[3];
    const float* w2     = (const float*)d_in[4];
    const float* b2     = (const float*)d_in[5];
    float* out = (float*)d_out;

    unsigned short* weff_sw = (unsigned short*)d_ws;    // 106496 bf16
    unsigned short* w2f     = weff_sw + NWB;            // 2048 bf16

    const int prep_total = NWB + NW2;                   // 108544
    prep_kernel<<<(prep_total + 255) / 256, 256, 0, stream>>>(conv_w, w1, w2, weff_sw, w2f);
    fused_mlp_kernel<<<BATCH / BM, NTHR, 0, stream>>>(x, b1, b2, weff_sw, w2f, out);
}